// Round 1
// 366.929 us; speedup vs baseline: 1.0415x; 1.0415x over previous
//
#include <hip/hip_runtime.h>
#include <hip/hip_bf16.h>

typedef __bf16 bf16x4 __attribute__((ext_vector_type(4)));
typedef __bf16 bf16x8 __attribute__((ext_vector_type(8)));
typedef float floatx4 __attribute__((ext_vector_type(4)));

#define GLD16(gp, lp) __builtin_amdgcn_global_load_lds(                      \
    (const __attribute__((address_space(1))) void*)(gp),                     \
    (__attribute__((address_space(3))) void*)(lp), 16, 0, 0)

constexpr int Mdim = 16384;   // B*S
constexpr int Ndim = 3072;    // 3*D
constexpr int Kdim = 1024;    // D

static __device__ __forceinline__ bf16x8 cvt8(floatx4 lo, floatx4 hi) {
    bf16x8 r;
#pragma unroll
    for (int e = 0; e < 4; ++e) { r[e] = (__bf16)lo[e]; r[e + 4] = (__bf16)hi[e]; }
    return r;
}

// ===========================================================================
// FAST PATH (requires ws_size >= 40 MB)
// ===========================================================================

// --- prep 1: W_eff = W_qkv + LoRA fold, fp32 accumulate -> bf16 ------------
__global__ __launch_bounds__(256) void build_weff(
    const float* __restrict__ Wqkv,   // 3072 x 1024
    const float* __restrict__ Waq,    // 16 x 1024
    const float* __restrict__ Wbq,    // 1024 x 16
    const float* __restrict__ Wav,    // 16 x 1024
    const float* __restrict__ Wbv,    // 1024 x 16
    __hip_bfloat16* __restrict__ Weff)
{
    const int idx = (blockIdx.x * 256 + threadIdx.x) * 4;  // e*1024 + d
    const int e = idx >> 10;
    const int d = idx & 1023;
    floatx4 v = *(const floatx4*)(Wqkv + idx);
    if (e < 1024) {
#pragma unroll
        for (int r = 0; r < 16; ++r) {
            const float wb = Wbq[e * 16 + r];
            floatx4 wa = *(const floatx4*)(Waq + r * 1024 + d);
#pragma unroll
            for (int q = 0; q < 4; ++q) v[q] += wb * wa[q];
        }
    } else if (e >= 2048) {
        const int e2 = e - 2048;
#pragma unroll
        for (int r = 0; r < 16; ++r) {
            const float wb = Wbv[e2 * 16 + r];
            floatx4 wa = *(const floatx4*)(Wav + r * 1024 + d);
#pragma unroll
            for (int q = 0; q < 4; ++q) v[q] += wb * wa[q];
        }
    }
    bf16x4 o;
#pragma unroll
    for (int q = 0; q < 4; ++q) o[q] = (__bf16)v[q];
    *(bf16x4*)(Weff + idx) = o;
}

// --- prep 2: x fp32 -> bf16 -------------------------------------------------
__global__ __launch_bounds__(256) void cvt_x(
    const float* __restrict__ x, __hip_bfloat16* __restrict__ xb)
{
    const size_t idx = ((size_t)blockIdx.x * 256 + threadIdx.x) * 8;
    bf16x8 r = cvt8(*(const floatx4*)(x + idx), *(const floatx4*)(x + idx + 4));
    *(bf16x8*)(xb + idx) = r;
}

// --- main GEMM: 256x256 tile, BK=64, 8 waves, 4-phase/K-tile schedule ------
// T1 (XCD swizzle) + T2 (st-16 XOR bank swizzle, both-sides) + T3/T4
// (phase interleave w/ counted vmcnt, never 0 in main loop) + T5 (setprio).
__global__ __launch_bounds__(512, 2) void gemm_bf16_8ph(
    const __hip_bfloat16* __restrict__ A,     // M x K bf16
    const __hip_bfloat16* __restrict__ Bw,    // N x K bf16 (W_eff)
    const float* __restrict__ bias,           // N fp32
    float* __restrict__ C)                    // M x N fp32
{
    constexpr int NT = Kdim / 64;                     // 16 K-tiles
    __shared__ __hip_bfloat16 lds[2][2][256 * 64];    // [buf][A/B][row*64+col] 128 KiB

    const int t    = threadIdx.x;
    const int wid  = t >> 6;
    const int lane = t & 63;
    const int wm   = wid >> 2;        // 2 wave-rows  (128 rows each)
    const int wn   = wid & 3;         // 4 wave-cols  (64 cols each)

    // XCD-aware block swizzle (768 blocks, 768 % 8 == 0 -> bijective)
    constexpr int NWG = (Mdim / 256) * (Ndim / 256);  // 768
    const int bid = (blockIdx.x & 7) * (NWG >> 3) + (blockIdx.x >> 3);
    const int bx  = bid % (Ndim / 256);
    const int by  = bid / (Ndim / 256);
    const int m0  = by * 256;
    const int n0  = bx * 256;

    // --- staging geometry: LDS dest is LINEAR (base + t*16); the bank
    // swizzle is applied by permuting the GLOBAL source column (rule #21).
    // half-tile = 128 rows x 64 cols bf16 = 16 KiB = 2 gld_lds/thread.
    const int srow0 = t >> 3;                              // row (c=0) in half
    const int scb_s = ((t & 7) * 16) ^ ((srow0 & 7) << 4); // swizzled src colbyte

#define STAGE_HALF(G, R0, h, nb_, mat, kt_) do {                               \
    const __hip_bfloat16* _g = (G) + (size_t)((R0) + (h) * 128 + srow0) * Kdim \
                               + (kt_) * 64 + (scb_s >> 1);                    \
    char* _l = (char*)&lds[nb_][mat][0] + (h) * 16384 + t * 16;                \
    GLD16(_g, _l);                                                             \
    GLD16(_g + (size_t)64 * Kdim, _l + 8192);                                  \
} while (0)

    // --- frag-read geometry: A/B operand fm = lane&15 (row), k = (lane>>4)*8+j.
    // row stride in LDS = 128 B -> XOR byte bits 4-6 with (row&7)<<4.
    // row&7 == fm&7 for every frag row (wm*128, mq*64, i*16 all ≡ 0 mod 8).
    const int fm   = lane & 15;
    const int fk2  = (lane >> 4) * 16;        // fk * 2 bytes
    const int fxor = (fm & 7) << 4;
    const int cbs0 = fk2 ^ fxor;              // kk = 0 (k 0..31)
    const int cbs1 = (64 + fk2) ^ fxor;       // kk = 1 (k 32..63)

    floatx4 acc[8][4];
#pragma unroll
    for (int i = 0; i < 8; ++i)
#pragma unroll
        for (int j = 0; j < 4; ++j)
            acc[i][j] = (floatx4){0.f, 0.f, 0.f, 0.f};

#define MFMA_QUAD(mq, nq, BQ)                                                  \
    __builtin_amdgcn_s_setprio(1);                                             \
    _Pragma("unroll")                                                          \
    for (int i = 0; i < 4; ++i)                                                \
        _Pragma("unroll")                                                      \
        for (int j = 0; j < 2; ++j) {                                          \
            acc[(mq) * 4 + i][(nq) * 2 + j] =                                  \
                __builtin_amdgcn_mfma_f32_16x16x32_bf16(                       \
                    aq[i][0], BQ[j][0], acc[(mq) * 4 + i][(nq) * 2 + j], 0, 0, 0); \
            acc[(mq) * 4 + i][(nq) * 2 + j] =                                  \
                __builtin_amdgcn_mfma_f32_16x16x32_bf16(                       \
                    aq[i][1], BQ[j][1], acc[(mq) * 4 + i][(nq) * 2 + j], 0, 0, 0); \
        }                                                                      \
    __builtin_amdgcn_s_setprio(0);

    // prologue: stage tile 0 into buf 0 (8 loads/thread)
    STAGE_HALF(A,  m0, 0, 0, 0, 0);
    STAGE_HALF(A,  m0, 1, 0, 0, 0);
    STAGE_HALF(Bw, n0, 0, 0, 1, 0);
    STAGE_HALF(Bw, n0, 1, 0, 1, 0);

    bf16x8 aq[4][2], bq0[2][2], bq1[2][2];

    for (int kt = 0; kt < NT; ++kt) {
        const int nb = kt & 1;
        const char* Ab = (const char*)&lds[nb][0][0];
        const char* Bb = (const char*)&lds[nb][1][0];

#define LDA8(i, mq, kk) (*(const bf16x8*)(Ab + ((wm * 128 + (mq) * 64 + (i) * 16 + fm) * 128 + cbs##kk)))
#define LDB8(j, nq, kk) (*(const bf16x8*)(Bb + ((wn * 64 + (nq) * 32 + (j) * 16 + fm) * 128 + cbs##kk)))

        // ---- phase 0: quad (0,0). Stage A0,B0 of t+1; counted vmcnt(4):
        // the 4 newest loads (just issued) may stay in flight; everything
        // older (= all 8 loads of tile t) is forced landed before barrier.
        if (kt + 1 < NT) {
            STAGE_HALF(A,  m0, 0, nb ^ 1, 0, kt + 1);
            STAGE_HALF(Bw, n0, 0, nb ^ 1, 1, kt + 1);
            asm volatile("s_waitcnt vmcnt(4)" ::: "memory");
        } else {
            asm volatile("s_waitcnt vmcnt(0)" ::: "memory");   // drain, once
        }
        __builtin_amdgcn_s_barrier();
#pragma unroll
        for (int i = 0; i < 4; ++i) { aq[i][0] = LDA8(i, 0, 0); aq[i][1] = LDA8(i, 0, 1); }
#pragma unroll
        for (int j = 0; j < 2; ++j) { bq0[j][0] = LDB8(j, 0, 0); bq0[j][1] = LDB8(j, 0, 1); }
        MFMA_QUAD(0, 0, bq0)
        __builtin_amdgcn_s_barrier();

        // ---- phase 1: quad (0,1) ----
#pragma unroll
        for (int j = 0; j < 2; ++j) { bq1[j][0] = LDB8(j, 1, 0); bq1[j][1] = LDB8(j, 1, 1); }
        if (kt + 1 < NT) STAGE_HALF(A, m0, 1, nb ^ 1, 0, kt + 1);
        __builtin_amdgcn_s_barrier();
        MFMA_QUAD(0, 1, bq1)
        __builtin_amdgcn_s_barrier();

        // ---- phase 2: quad (1,0) ----
#pragma unroll
        for (int i = 0; i < 4; ++i) { aq[i][0] = LDA8(i, 1, 0); aq[i][1] = LDA8(i, 1, 1); }
        if (kt + 1 < NT) STAGE_HALF(Bw, n0, 1, nb ^ 1, 1, kt + 1);
        __builtin_amdgcn_s_barrier();
        MFMA_QUAD(1, 0, bq0)
        __builtin_amdgcn_s_barrier();

        // ---- phase 3: quad (1,1) ----
        MFMA_QUAD(1, 1, bq1)
        __builtin_amdgcn_s_barrier();

#undef LDA8
#undef LDB8
    }

    // epilogue: C/D layout col(n)=lane&15, row(m)=(lane>>4)*4 + reg
    const int cn = lane & 15;
    const int cm = (lane >> 4) * 4;
    float bv[4];
#pragma unroll
    for (int j = 0; j < 4; ++j)
        bv[j] = bias[n0 + wn * 64 + j * 16 + cn];

#pragma unroll
    for (int mi = 0; mi < 8; ++mi) {
        const int m = m0 + wm * 128 + mi * 16 + cm;
#pragma unroll
        for (int ni = 0; ni < 4; ++ni) {
            const int n = n0 + wn * 64 + ni * 16 + cn;
            const size_t base = (size_t)m * Ndim + n;
#pragma unroll
            for (int r = 0; r < 4; ++r)
                C[base + (size_t)r * Ndim] = acc[mi][ni][r] + bv[ni];
        }
    }
#undef STAGE_HALF
#undef MFMA_QUAD
}

// ===========================================================================
// FALLBACK PATH (R2, proven): used only if ws_size < 40 MB
// ===========================================================================

__global__ __launch_bounds__(256, 2) void gemm_bias_f32(
    const float* __restrict__ A, const float* __restrict__ Bw,
    const float* __restrict__ bias, float* __restrict__ C)
{
    constexpr int TK = 32;
    __shared__ __hip_bfloat16 As[128 * TK];
    __shared__ __hip_bfloat16 Bs[128 * TK];

    const int t    = threadIdx.x;
    const int wave = t >> 6;
    const int lane = t & 63;
    const int bx   = blockIdx.x % (Ndim / 128);
    const int by   = blockIdx.x / (Ndim / 128);
    const int m0   = by * 128;
    const int n0   = bx * 128;
    const int wm   = wave >> 1;
    const int wn   = wave & 1;
    const int srow = wave * 16 + (lane >> 2);
    const int scol = (lane & 3) * 8;

    const float* Ag0 = A  + (size_t)(m0 + srow) * Kdim + scol;
    const float* Ag1 = Ag0 + (size_t)64 * Kdim;
    const float* Bg0 = Bw + (size_t)(n0 + srow) * Kdim + scol;
    const float* Bg1 = Bg0 + (size_t)64 * Kdim;

    __hip_bfloat16* Al0 = &As[srow * TK + scol];
    __hip_bfloat16* Al1 = &As[(srow + 64) * TK + scol];
    __hip_bfloat16* Bl0 = &Bs[srow * TK + scol];
    __hip_bfloat16* Bl1 = &Bs[(srow + 64) * TK + scol];

    const int fm = lane & 15;
    const int fk = (lane >> 4) * 8;

    floatx4 acc[4][4];
#pragma unroll
    for (int i = 0; i < 4; ++i)
#pragma unroll
        for (int j = 0; j < 4; ++j)
            acc[i][j] = (floatx4){0.f, 0.f, 0.f, 0.f};

    for (int kt = 0; kt < Kdim; kt += TK) {
        bf16x8 a0 = cvt8(*(const floatx4*)(Ag0 + kt), *(const floatx4*)(Ag0 + kt + 4));
        bf16x8 a1 = cvt8(*(const floatx4*)(Ag1 + kt), *(const floatx4*)(Ag1 + kt + 4));
        bf16x8 b0 = cvt8(*(const floatx4*)(Bg0 + kt), *(const floatx4*)(Bg0 + kt + 4));
        bf16x8 b1 = cvt8(*(const floatx4*)(Bg1 + kt), *(const floatx4*)(Bg1 + kt + 4));
        __syncthreads();
        *(bf16x8*)Al0 = a0;
        *(bf16x8*)Al1 = a1;
        *(bf16x8*)Bl0 = b0;
        *(bf16x8*)Bl1 = b1;
        __syncthreads();

        bf16x8 af[4], bfr[4];
#pragma unroll
        for (int i = 0; i < 4; ++i) {
            af[i]  = *(const bf16x8*)&As[(wm * 64 + i * 16 + fm) * TK + fk];
            bfr[i] = *(const bf16x8*)&Bs[(wn * 64 + i * 16 + fm) * TK + fk];
        }
#pragma unroll
        for (int i = 0; i < 4; ++i)
#pragma unroll
            for (int j = 0; j < 4; ++j)
                acc[i][j] = __builtin_amdgcn_mfma_f32_16x16x32_bf16(af[i], bfr[j], acc[i][j], 0, 0, 0);
    }

    const int cn = lane & 15;
    const int cm = (lane >> 4) * 4;
    float bv[4];
#pragma unroll
    for (int j = 0; j < 4; ++j)
        bv[j] = bias[n0 + wn * 64 + j * 16 + cn];
#pragma unroll
    for (int i = 0; i < 4; ++i) {
        const int m = m0 + wm * 64 + i * 16 + cm;
#pragma unroll
        for (int j = 0; j < 4; ++j) {
            const int n = n0 + wn * 64 + j * 16 + cn;
            const size_t base = (size_t)m * Ndim + n;
#pragma unroll
            for (int r = 0; r < 4; ++r)
                C[base + (size_t)r * Ndim] = acc[i][j][r] + bv[j];
        }
    }
}

__global__ __launch_bounds__(256) void lora_rmw(
    const float* __restrict__ x,
    const float* __restrict__ Waq, const float* __restrict__ Wbq,
    const float* __restrict__ Wav, const float* __restrict__ Wbv,
    float* __restrict__ out)
{
    __shared__ float Pq[64][16];
    __shared__ float Pv[64][16];
    const int t  = threadIdx.x;
    const int m0 = blockIdx.x * 64;
    {
        const int row = t >> 2;
        const int r0  = (t & 3) * 4;
        float accq[4] = {0.f, 0.f, 0.f, 0.f};
        float accv[4] = {0.f, 0.f, 0.f, 0.f};
        const float* xr = x + (size_t)(m0 + row) * Kdim;
        for (int d = 0; d < Kdim; d += 4) {
            floatx4 xv = *(const floatx4*)(xr + d);
#pragma unroll
            for (int rr = 0; rr < 4; ++rr) {
                floatx4 wq = *(const floatx4*)(Waq + (size_t)(r0 + rr) * Kdim + d);
                floatx4 wv = *(const floatx4*)(Wav + (size_t)(r0 + rr) * Kdim + d);
#pragma unroll
                for (int e = 0; e < 4; ++e) {
                    accq[rr] += xv[e] * wq[e];
                    accv[rr] += xv[e] * wv[e];
                }
            }
        }
#pragma unroll
        for (int rr = 0; rr < 4; ++rr) {
            Pq[row][r0 + rr] = accq[rr];
            Pv[row][r0 + rr] = accv[rr];
        }
    }
    __syncthreads();
    const int col  = t * 8;
    const bool isq = col < 1024;
    const int nn0  = isq ? col : col - 1024;
    const int n    = isq ? col : col + 1024;
    const float* Wb = isq ? Wbq : Wbv;
    for (int row = 0; row < 64; ++row) {
        const float* P = isq ? Pq[row] : Pv[row];
        const size_t off = (size_t)(m0 + row) * Ndim + n;
        floatx4 o0 = *(const floatx4*)(out + off);
        floatx4 o1 = *(const floatx4*)(out + off + 4);
#pragma unroll
        for (int i = 0; i < 8; ++i) {
            floatx4 w0 = *(const floatx4*)(Wb + (size_t)(nn0 + i) * 16);
            floatx4 w1 = *(const floatx4*)(Wb + (size_t)(nn0 + i) * 16 + 4);
            floatx4 w2 = *(const floatx4*)(Wb + (size_t)(nn0 + i) * 16 + 8);
            floatx4 w3 = *(const floatx4*)(Wb + (size_t)(nn0 + i) * 16 + 12);
            float s = 0.f;
#pragma unroll
            for (int r = 0; r < 4; ++r)
                s += P[r] * w0[r] + P[r + 4] * w1[r] + P[r + 8] * w2[r] + P[r + 12] * w3[r];
            if (i < 4) o0[i] += s; else o1[i - 4] += s;
        }
        *(floatx4*)(out + off)     = o0;
        *(floatx4*)(out + off + 4) = o1;
    }
}

extern "C" void kernel_launch(void* const* d_in, const int* in_sizes, int n_in,
                              void* d_out, int out_size, void* d_ws, size_t ws_size,
                              hipStream_t stream)
{
    (void)in_sizes; (void)n_in; (void)out_size;
    const float* x    = (const float*)d_in[0];
    const float* Wqkv = (const float*)d_in[1];
    const float* bqkv = (const float*)d_in[2];
    const float* Waq  = (const float*)d_in[3];
    const float* Wbq  = (const float*)d_in[4];
    const float* Wav  = (const float*)d_in[5];
    const float* Wbv  = (const float*)d_in[6];
    float* out = (float*)d_out;

    const size_t WEFF_BYTES = (size_t)Ndim * Kdim * sizeof(__hip_bfloat16); // 6.3 MB
    const size_t XB_BYTES   = (size_t)Mdim * Kdim * sizeof(__hip_bfloat16); // 33.5 MB

    if (ws_size >= WEFF_BYTES + XB_BYTES) {
        // fast path: fold LoRA into bf16 W_eff, bf16 x, single MFMA GEMM
        __hip_bfloat16* Weff = (__hip_bfloat16*)d_ws;
        __hip_bfloat16* xb   = (__hip_bfloat16*)((char*)d_ws + WEFF_BYTES);
        build_weff<<<(Ndim * Kdim / 4) / 256, 256, 0, stream>>>(Wqkv, Waq, Wbq, Wav, Wbv, Weff);
        cvt_x<<<(int)(((size_t)Mdim * Kdim / 8) / 256), 256, 0, stream>>>(x, xb);
        gemm_bf16_8ph<<<(Mdim / 256) * (Ndim / 256), 512, 0, stream>>>(xb, Weff, bqkv, out);
    } else {
        // fallback: R2 proven path (no scratch)
        gemm_bias_f32<<<(Mdim / 128) * (Ndim / 128), 256, 0, stream>>>(x, Wqkv, bqkv, out);
        lora_rmw<<<Mdim / 64, 256, 0, stream>>>(x, Waq, Wbq, Wav, Wbv, out);
    }
}